// Round 5
// baseline (66.565 us; speedup 1.0000x reference)
//
#include <hip/hip_runtime.h>
#include <hip/hip_bf16.h>

#define ALPHA 0.25f
#define DELTA 0.5f
#define GRID  2048
#define BLOCK 256

#define CNT_BITS 12              // low 12 bits: block-arrival count (2048 <= 4095)
#define CNT_MASK 0xFFFull
#define SCALE    1048576.0       // 2^20 fixed-point scale for the sum field

// ---------------------------------------------------------------------------
// Single fused kernel, ZERO fences:
//  - main loop identical to round 1 (best measured: 50.4 us total)
//  - each block folds its f32 partial into a u64 fixed-point value and does
//    ONE packed atomicAdd:  acc += (scaled << 12) | 1.
//    The atomic return value carries the sum of all earlier blocks, so the
//    last-arriving block ((old & CNT_MASK) == GRID-1) already HOLDS the full
//    total -- no fence, no acquire loop, no second kernel.
//  - integer atomics commute exactly -> bitwise-deterministic output.
//  - acc word is zeroed by an 8-byte hipMemsetAsync before each launch
//    (graph-capture legal, verified in round 3).
// ---------------------------------------------------------------------------
__global__ void __launch_bounds__(BLOCK)
dafl_fused_kernel(const float* __restrict__ y_pred,
                  const float* __restrict__ y_true,
                  unsigned long long* __restrict__ acc_pack,
                  float* __restrict__ out,
                  long long n4,            // number of float4 elements
                  double inv_n_scaled)     // 1 / (n * 2^20)
{
    const float4* __restrict__ p4 = reinterpret_cast<const float4*>(y_pred);
    const float4* __restrict__ t4 = reinterpret_cast<const float4*>(y_true);

    float acc = 0.0f;
    long long idx = (long long)blockIdx.x * blockDim.x + threadIdx.x;
    long long stride = (long long)gridDim.x * blockDim.x;

    for (long long i = idx; i < n4; i += stride) {
        float4 p = p4[i];
        float4 t = t4[i];

        #pragma unroll
        for (int j = 0; j < 4; ++j) {
            float pp = (&p.x)[j];
            float tt = (&t.x)[j];

            // class weight: lut[clip(round(t),0,3)], round-half-to-even
            float r = rintf(tt);
            r = fminf(fmaxf(r, 0.0f), 3.0f);
            int cls = (int)r;
            float w = (cls == 0) ? 1.0f
                    : (cls == 1) ? 4.0f
                    : (cls == 2) ? 3.0f
                    :              2.0f;

            float d = fabsf(pp - tt);
            float f = fminf(d * 2.0f, 1.0f);               // clip(d/0.5,0,1)
            f = f * f;                                     // ^GAMMA(=2)
            float base = (d < DELTA) ? (d * d) : (d - 0.25f);  // huber beta=0.5

            acc += ALPHA * f * base * w;
        }
    }

    // wave-level reduction (64 lanes)
    #pragma unroll
    for (int off = 32; off > 0; off >>= 1)
        acc += __shfl_down(acc, off, 64);

    // block-level: 4 waves
    __shared__ float smem[4];
    const int lane = threadIdx.x & 63;
    const int wave = threadIdx.x >> 6;
    if (lane == 0) smem[wave] = acc;
    __syncthreads();

    if (threadIdx.x == 0) {
        float s = smem[0] + smem[1] + smem[2] + smem[3];

        // fixed-point encode: sum field (high 52 bits) + count field (low 12)
        unsigned long long scaled =
            (unsigned long long)((double)s * SCALE + 0.5);
        unsigned long long old =
            atomicAdd(acc_pack, (scaled << CNT_BITS) | 1ull);

        if ((old & CNT_MASK) == (unsigned long long)(GRID - 1)) {
            // last block: old's high field = sum of the other 2047 blocks
            unsigned long long total = (old >> CNT_BITS) + scaled;
            out[0] = (float)((double)total * inv_n_scaled);
        }
    }
}

extern "C" void kernel_launch(void* const* d_in, const int* in_sizes, int n_in,
                              void* d_out, int out_size, void* d_ws, size_t ws_size,
                              hipStream_t stream) {
    const float* y_pred = (const float*)d_in[0];
    const float* y_true = (const float*)d_in[1];
    float* out = (float*)d_out;
    unsigned long long* acc_pack = (unsigned long long*)d_ws;

    long long n = (long long)in_sizes[0];   // B*N = 2^25
    long long n4 = n >> 2;

    // reset the packed {count, sum} word (async memset: capture-legal)
    hipMemsetAsync(acc_pack, 0, sizeof(unsigned long long), stream);

    dafl_fused_kernel<<<GRID, BLOCK, 0, stream>>>(
        y_pred, y_true, acc_pack, out, n4,
        1.0 / ((double)n * SCALE));
}

// Round 6
// 48.403 us; speedup vs baseline: 1.3752x; 1.3752x over previous
//
#include <hip/hip_runtime.h>
#include <hip/hip_bf16.h>

#define ALPHA 0.25f
#define DELTA 0.5f
#define GRID  2048
#define BLOCK 256

// ---------------------------------------------------------------------------
// Kernel 1: grid-stride elementwise loss (round-1 structure: simple loop,
// 12 VGPR, max occupancy), block partial -> d_ws. int32 indices (n4 = 2^23
// fits easily; saves 64-bit address VALU ops).
// ---------------------------------------------------------------------------
__global__ void __launch_bounds__(BLOCK)
dafl_partial_kernel(const float* __restrict__ y_pred,
                    const float* __restrict__ y_true,
                    float* __restrict__ partials,
                    int n4)   // number of float4 elements
{
    const float4* __restrict__ p4 = reinterpret_cast<const float4*>(y_pred);
    const float4* __restrict__ t4 = reinterpret_cast<const float4*>(y_true);

    float acc = 0.0f;
    const int idx    = blockIdx.x * BLOCK + threadIdx.x;
    const int stride = GRID * BLOCK;

    for (int i = idx; i < n4; i += stride) {
        float4 p = p4[i];
        float4 t = t4[i];

        #pragma unroll
        for (int j = 0; j < 4; ++j) {
            float pp = (&p.x)[j];
            float tt = (&t.x)[j];

            // class weight: lut[clip(round(t),0,3)], round-half-to-even
            float r = rintf(tt);
            r = fminf(fmaxf(r, 0.0f), 3.0f);
            int cls = (int)r;
            float w = (cls == 0) ? 1.0f
                    : (cls == 1) ? 4.0f
                    : (cls == 2) ? 3.0f
                    :              2.0f;

            float d = fabsf(pp - tt);
            float f = fminf(d * 2.0f, 1.0f);               // clip(d/0.5,0,1)
            f = f * f;                                     // ^GAMMA(=2)
            float base = (d < DELTA) ? (d * d) : (d - 0.25f);  // huber beta=0.5

            acc += ALPHA * f * base * w;
        }
    }

    // wave-level reduction (64 lanes)
    #pragma unroll
    for (int off = 32; off > 0; off >>= 1)
        acc += __shfl_down(acc, off, 64);

    __shared__ float smem[4];
    const int lane = threadIdx.x & 63;
    const int wave = threadIdx.x >> 6;
    if (lane == 0) smem[wave] = acc;
    __syncthreads();

    if (threadIdx.x == 0)
        partials[blockIdx.x] = smem[0] + smem[1] + smem[2] + smem[3];
}

// ---------------------------------------------------------------------------
// Kernel 2: one wave (64 lanes), float4 loads of the 2048 partials
// (8 float4 per lane), shuffle reduce, write mean. No LDS, no syncthreads.
// ---------------------------------------------------------------------------
__global__ void __launch_bounds__(64)
dafl_final_kernel(const float* __restrict__ partials,
                  float* __restrict__ out,
                  float inv_n)
{
    const float4* __restrict__ q4 = reinterpret_cast<const float4*>(partials);

    float acc = 0.0f;
    #pragma unroll
    for (int k = 0; k < (GRID / 4) / 64; ++k) {       // 8 iterations
        float4 v = q4[k * 64 + threadIdx.x];
        acc += (v.x + v.y) + (v.z + v.w);
    }

    #pragma unroll
    for (int off = 32; off > 0; off >>= 1)
        acc += __shfl_down(acc, off, 64);

    if (threadIdx.x == 0)
        out[0] = acc * inv_n;
}

extern "C" void kernel_launch(void* const* d_in, const int* in_sizes, int n_in,
                              void* d_out, int out_size, void* d_ws, size_t ws_size,
                              hipStream_t stream) {
    const float* y_pred = (const float*)d_in[0];
    const float* y_true = (const float*)d_in[1];
    float* out = (float*)d_out;
    float* partials = (float*)d_ws;

    long long n = (long long)in_sizes[0];   // B*N = 2^25
    int n4 = (int)(n >> 2);

    dafl_partial_kernel<<<GRID, BLOCK, 0, stream>>>(y_pred, y_true, partials, n4);
    dafl_final_kernel<<<1, 64, 0, stream>>>(partials, out, (float)(1.0 / (double)n));
}